// Round 4
// baseline (179.380 us; speedup 1.0000x reference)
//
#include <hip/hip_runtime.h>
#include <float.h>

constexpr int Bn = 8, Qn = 32768, Tn = 64, MT = 4;
constexpr int BLOCK = 256;
constexpr int CHUNKS = 64;              // Q-chunks per (b,which)
constexpr int CHUNK  = Qn / CHUNKS;     // 512 boxes per block
constexpr int PARTS  = BLOCK / 64;      // 4 waves per block
constexpr int SUB    = CHUNK / PARTS;   // 128 boxes scanned per wave
constexpr int NBW    = Bn * 2;          // 16 (b, which) slabs
constexpr int FIN    = 4;               // finisher blocks per bw (tickets 60..63)

// compare-exchange on (val, idx), lexicographic -> stable top_k tie-break (cold path)
__device__ __forceinline__ void cmpx(float& av, int& ai, float& bv, int& bi) {
    bool sw = (bv < av) || ((bv == av) && (bi < ai));
    float v0 = sw ? bv : av; int i0 = sw ? bi : ai;
    float v1 = sw ? av : bv; int i1 = sw ? ai : bi;
    av = v0; ai = i0; bv = v1; bi = i1;
}

// both lists sorted ascending; leaves 4 smallest of union in a, sorted. (cold path)
__device__ __forceinline__ void merge4(float a_v[4], int a_i[4],
                                       const float b_v[4], const int b_i[4]) {
    float mv[4]; int mi[4];
#pragma unroll
    for (int k = 0; k < 4; ++k) {
        float bv = b_v[3 - k]; int bi = b_i[3 - k];
        bool ta = (a_v[k] < bv) || ((a_v[k] == bv) && (a_i[k] < bi));
        mv[k] = ta ? a_v[k] : bv;
        mi[k] = ta ? a_i[k] : bi;
    }
    cmpx(mv[0], mi[0], mv[2], mi[2]);
    cmpx(mv[1], mi[1], mv[3], mi[3]);
    cmpx(mv[0], mi[0], mv[1], mi[1]);
    cmpx(mv[2], mi[2], mv[3], mi[3]);
#pragma unroll
    for (int k = 0; k < 4; ++k) { a_v[k] = mv[k]; a_i[k] = mi[k]; }
}

// Fused: block = (chunk c, which, b). Lane = target, wave = quarter of chunk.
// Partials released via threadfence + per-bw ticket; last 4 blocks of each bw
// merge that bw's 64 targets (4 waves x 4 butterflies each).
__global__ __launch_bounds__(BLOCK) void matcher_fused(
        const float* __restrict__ pred, const float* __restrict__ anch,
        const float* __restrict__ gt, float2* __restrict__ partial,
        int* __restrict__ cnt, int* __restrict__ out_i, int* __restrict__ out_j) {
    const int c     = blockIdx.x;
    const int which = blockIdx.y;
    const int b     = blockIdx.z;
    const int tid   = threadIdx.x;
    const int bw    = b * 2 + which;

    __shared__ float4 sbox[CHUNK];              // 8 KB: cxcywh-converted boxes
    __shared__ float2 sred[PARTS][64][5];       // pad 4->5: break write conflicts
    __shared__ int s_old;

    const float4* bp = (const float4*)((which ? anch : pred) + (size_t)b * Qn * 4)
                       + (size_t)c * CHUNK;
#pragma unroll
    for (int i = tid; i < CHUNK; i += BLOCK) {
        float4 p = bp[i];
        sbox[i] = make_float4((p.x + p.z) * 0.5f, (p.y + p.w) * 0.5f,
                              p.z - p.x, p.w - p.y);
    }

    const int t    = tid & 63;     // this lane's target
    const int part = tid >> 6;     // this wave's sub-range of the chunk
    const float4 g = *(const float4*)(gt + ((size_t)b * Tn + t) * 4);
    const float gcx = (g.x + g.z) * 0.5f;
    const float gcy = (g.y + g.w) * 0.5f;
    const float gw  = g.z - g.x;
    const float gh  = g.w - g.y;

    __syncthreads();

    float v[4]  = {FLT_MAX, FLT_MAX, FLT_MAX, FLT_MAX};
    int   ix[4] = {0x7fffffff, 0x7fffffff, 0x7fffffff, 0x7fffffff};

    const int j0 = part * SUB;
    const int qbase = c * CHUNK + j0;
#pragma unroll 8
    for (int jj = 0; jj < SUB; ++jj) {
        float4 p = sbox[j0 + jj];              // wave-uniform addr -> LDS broadcast
        float d0 = p.x - gcx, d1 = p.y - gcy, d2 = p.z - gw, d3 = p.w - gh;
        float cst = fabsf(d0) + fabsf(d1);     // abs folds into VOP3 src modifiers
        cst += fabsf(d2);
        cst += fabsf(d3);
        const int q = qbase + jj;
        // values: compare-free sorted insert via min/med3
        float n0 = fminf(v[0], cst);
        float n1 = __builtin_amdgcn_fmed3f(v[0], v[1], cst);
        float n2 = __builtin_amdgcn_fmed3f(v[1], v[2], cst);
        float n3 = __builtin_amdgcn_fmed3f(v[2], v[3], cst);
        // indices: strict '<' keeps earlier idx on exact ties (top_k stability)
        bool b0 = cst < v[0], b1 = cst < v[1], b2 = cst < v[2], b3 = cst < v[3];
        int i3 = b2 ? ix[2] : (b3 ? q : ix[3]);
        int i2 = b1 ? ix[1] : (b2 ? q : ix[2]);
        int i1 = b0 ? ix[0] : (b1 ? q : ix[1]);
        int i0 = b0 ? q : ix[0];
        v[0] = n0; v[1] = n1; v[2] = n2; v[3] = n3;
        ix[0] = i0; ix[1] = i1; ix[2] = i2; ix[3] = i3;
    }

    // cross-wave (4 parts) merge per target via LDS
#pragma unroll
    for (int k = 0; k < 4; ++k)
        sred[part][t][k] = make_float2(v[k], __int_as_float(ix[k]));
    __syncthreads();

    if (tid < 64) {   // wave 0: lane = t; its own part-0 list already in v/ix
#pragma unroll
        for (int p2 = 1; p2 < PARTS; ++p2) {
            float bv[4]; int bi[4];
#pragma unroll
            for (int k = 0; k < 4; ++k) {
                float2 e = sred[p2][t][k];
                bv[k] = e.x; bi[k] = __float_as_int(e.y);
            }
            merge4(v, ix, bv, bi);
        }
        // layout [bw][chunk][t][4] -> this wave's 64 lanes write a contiguous 2 KB run
        float2* dst = partial + (((size_t)bw * CHUNKS + c) * 64 + t) * 4;
#pragma unroll
        for (int k = 0; k < 4; ++k)
            dst[k] = make_float2(v[k], __int_as_float(ix[k]));
    }

    // ---- release + ticket ----
    __threadfence();                       // make partials visible device-wide
    if (tid == 0) s_old = atomicAdd(&cnt[bw], 1);
    __syncthreads();
    const int old = s_old;
    if (old < CHUNKS - FIN) return;        // tickets 0..59: done

    // finisher: wait until all 64 chunks of this bw have released
    if (tid == 0) {
        while (__hip_atomic_load(&cnt[bw], __ATOMIC_RELAXED,
                                 __HIP_MEMORY_SCOPE_AGENT) < CHUNKS)
            __builtin_amdgcn_s_sleep(2);
    }
    __syncthreads();
    __threadfence();                       // acquire: see all bw partials

    const int fidx = old - (CHUNKS - FIN); // 0..3
    const int lane = tid & 63;
    const int wv   = tid >> 6;
#pragma unroll
    for (int i = 0; i < 4; ++i) {
        const int tt = fidx * 16 + wv * 4 + i;
        // lane = chunk; load its 4 (val,idx) pairs for target tt
        const float4* src4 = (const float4*)(partial +
                (((size_t)bw * CHUNKS + lane) * 64 + tt) * 4);
        float4 e0 = src4[0], e1 = src4[1];
        float mv[4]; int mi[4];
        mv[0] = e0.x; mi[0] = __float_as_int(e0.y);
        mv[1] = e0.z; mi[1] = __float_as_int(e0.w);
        mv[2] = e1.x; mi[2] = __float_as_int(e1.y);
        mv[3] = e1.z; mi[3] = __float_as_int(e1.w);
#pragma unroll
        for (int d = 1; d < 64; d <<= 1) {
            float bv[4]; int bi[4];
#pragma unroll
            for (int k = 0; k < 4; ++k) {
                bv[k] = __shfl_xor(mv[k], d, 64);
                bi[k] = __shfl_xor(mi[k], d, 64);
            }
            merge4(mv, mi, bv, bi);
        }
        if (lane == 0) {
            const int base = ((b * Tn + tt) * 2 + which) * MT;
#pragma unroll
            for (int k = 0; k < 4; ++k) {
                out_i[base + k] = mi[k];
                out_j[base + k] = k;
            }
        }
    }
}

extern "C" void kernel_launch(void* const* d_in, const int* in_sizes, int n_in,
                              void* d_out, int out_size, void* d_ws, size_t ws_size,
                              hipStream_t stream) {
    const float* pred = (const float*)d_in[0];
    const float* anch = (const float*)d_in[1];
    const float* gt   = (const float*)d_in[2];
    int* out = (int*)d_out;
    float2* partial = (float2*)d_ws;                     // 16*64*64*4 float2 = 2 MB
    int* cnt = (int*)((char*)d_ws + (size_t)2 * 1024 * 1024);
    const int half = Bn * Tn * 2 * MT;                   // 4096: idx_i then idx_j

    hipMemsetAsync(cnt, 0, NBW * sizeof(int), stream);   // graph-legal memset node

    dim3 grid(CHUNKS, 2, Bn);                            // 1024 blocks, co-resident
    matcher_fused<<<grid, BLOCK, 0, stream>>>(pred, anch, gt, partial, cnt,
                                              out, out + half);
}

// Round 5
// 83.007 us; speedup vs baseline: 2.1610x; 2.1610x over previous
//
#include <hip/hip_runtime.h>
#include <float.h>

constexpr int Bn = 8, Qn = 32768, Tn = 64, MT = 4;
constexpr int BLOCK = 256;
constexpr int CHUNKS = 64;              // Q-chunks per (b,which); = 64 so stage2 lane <-> chunk
constexpr int CHUNK  = Qn / CHUNKS;     // 512 boxes per block
constexpr int PARTS  = BLOCK / 64;      // 4 waves per block
constexpr int SUB    = CHUNK / PARTS;   // 128 boxes scanned per wave

// compare-exchange on (val, idx), lexicographic -> stable top_k tie-break (cold path)
__device__ __forceinline__ void cmpx(float& av, int& ai, float& bv, int& bi) {
    bool sw = (bv < av) || ((bv == av) && (bi < ai));
    float v0 = sw ? bv : av; int i0 = sw ? bi : ai;
    float v1 = sw ? av : bv; int i1 = sw ? ai : bi;
    av = v0; ai = i0; bv = v1; bi = i1;
}

// both lists sorted ascending; leaves 4 smallest of union in a, sorted. (cold path)
__device__ __forceinline__ void merge4(float a_v[4], int a_i[4],
                                       const float b_v[4], const int b_i[4]) {
    float mv[4]; int mi[4];
#pragma unroll
    for (int k = 0; k < 4; ++k) {
        float bv = b_v[3 - k]; int bi = b_i[3 - k];
        bool ta = (a_v[k] < bv) || ((a_v[k] == bv) && (a_i[k] < bi));
        mv[k] = ta ? a_v[k] : bv;
        mi[k] = ta ? a_i[k] : bi;
    }
    cmpx(mv[0], mi[0], mv[2], mi[2]);
    cmpx(mv[1], mi[1], mv[3], mi[3]);
    cmpx(mv[0], mi[0], mv[1], mi[1]);
    cmpx(mv[2], mi[2], mv[3], mi[3]);
#pragma unroll
    for (int k = 0; k < 4; ++k) { a_v[k] = mv[k]; a_i[k] = mi[k]; }
}

// Stage 1: block = (chunk c, which, b). Lane = target, wave = quarter of chunk.
// Boxes loaded from HBM once per block, converted once, broadcast from LDS.
// NOTE (round 4): do NOT fuse stages with __threadfence + ticket — agent-scope
// fences emit per-wave L2 writeback/invalidate and serialized at ~146 us.
// The kernel boundary is the cheap device fence.
__global__ __launch_bounds__(BLOCK) void matcher_stage1(
        const float* __restrict__ pred, const float* __restrict__ anch,
        const float* __restrict__ gt, float2* __restrict__ partial) {
    const int c     = blockIdx.x;
    const int which = blockIdx.y;
    const int b     = blockIdx.z;
    const int tid   = threadIdx.x;

    __shared__ float4 sbox[CHUNK];              // 8 KB: cxcywh-converted boxes
    __shared__ float2 sred[PARTS][64][5];       // pad 4->5: break write conflicts

    const float4* bp = (const float4*)((which ? anch : pred) + (size_t)b * Qn * 4)
                       + (size_t)c * CHUNK;
#pragma unroll
    for (int i = tid; i < CHUNK; i += BLOCK) {
        float4 p = bp[i];
        sbox[i] = make_float4((p.x + p.z) * 0.5f, (p.y + p.w) * 0.5f,
                              p.z - p.x, p.w - p.y);
    }

    const int t    = tid & 63;     // this lane's target
    const int part = tid >> 6;     // this wave's sub-range of the chunk
    const float4 g = *(const float4*)(gt + ((size_t)b * Tn + t) * 4);
    const float gcx = (g.x + g.z) * 0.5f;
    const float gcy = (g.y + g.w) * 0.5f;
    const float gw  = g.z - g.x;
    const float gh  = g.w - g.y;

    __syncthreads();

    float v[4]  = {FLT_MAX, FLT_MAX, FLT_MAX, FLT_MAX};
    int   ix[4] = {0x7fffffff, 0x7fffffff, 0x7fffffff, 0x7fffffff};

    const int j0 = part * SUB;
    const int qbase = c * CHUNK + j0;
#pragma unroll 8
    for (int jj = 0; jj < SUB; ++jj) {
        float4 p = sbox[j0 + jj];              // wave-uniform addr -> LDS broadcast
        float d0 = p.x - gcx, d1 = p.y - gcy, d2 = p.z - gw, d3 = p.w - gh;
        float cst = fabsf(d0) + fabsf(d1);     // abs folds into VOP3 src modifiers
        cst += fabsf(d2);
        cst += fabsf(d3);
        const int q = qbase + jj;
        // values: compare-free sorted insert via min/med3
        float n0 = fminf(v[0], cst);
        float n1 = __builtin_amdgcn_fmed3f(v[0], v[1], cst);
        float n2 = __builtin_amdgcn_fmed3f(v[1], v[2], cst);
        float n3 = __builtin_amdgcn_fmed3f(v[2], v[3], cst);
        // indices: strict '<' keeps earlier idx on exact ties (top_k stability)
        bool b0 = cst < v[0], b1 = cst < v[1], b2 = cst < v[2], b3 = cst < v[3];
        int i3 = b2 ? ix[2] : (b3 ? q : ix[3]);
        int i2 = b1 ? ix[1] : (b2 ? q : ix[2]);
        int i1 = b0 ? ix[0] : (b1 ? q : ix[1]);
        int i0 = b0 ? q : ix[0];
        v[0] = n0; v[1] = n1; v[2] = n2; v[3] = n3;
        ix[0] = i0; ix[1] = i1; ix[2] = i2; ix[3] = i3;
    }

    // cross-wave (4 parts) merge per target via LDS
#pragma unroll
    for (int k = 0; k < 4; ++k)
        sred[part][t][k] = make_float2(v[k], __int_as_float(ix[k]));
    __syncthreads();

    if (tid < 64) {   // wave 0: lane = t; its own part-0 list already in v/ix
#pragma unroll
        for (int p2 = 1; p2 < PARTS; ++p2) {
            float bv[4]; int bi[4];
#pragma unroll
            for (int k = 0; k < 4; ++k) {
                float2 e = sred[p2][t][k];
                bv[k] = e.x; bi[k] = __float_as_int(e.y);
            }
            merge4(v, ix, bv, bi);
        }
        // layout [bw][chunk][t][4] -> this wave's 64 lanes write one contiguous 2 KB run
        const int bw = b * 2 + which;
        float2* dst = partial + (((size_t)bw * CHUNKS + c) * 64 + t) * 4;
#pragma unroll
        for (int k = 0; k < 4; ++k)
            dst[k] = make_float2(v[k], __int_as_float(ix[k]));
    }
}

// Stage 2: one wave per (b,which,t); lane = chunk; 6-step butterfly merge.
__global__ __launch_bounds__(BLOCK) void matcher_stage2(
        const float2* __restrict__ partial,
        int* __restrict__ out_i, int* __restrict__ out_j) {
    const int lane = threadIdx.x & 63;
    const int gwv  = blockIdx.x * (BLOCK / 64) + (threadIdx.x >> 6); // tuple 0..1023
    const int bw = gwv >> 6;
    const int t  = gwv & 63;

    // partial layout: [bw][chunk][t][4]; this lane's chunk = lane
    const float4* src4 = (const float4*)(partial + (((size_t)bw * CHUNKS + lane) * 64 + t) * 4);
    float4 e0 = src4[0], e1 = src4[1];     // 2x dwordx4 instead of 4x dwordx2
    float v[4]; int ix[4];
    v[0] = e0.x; ix[0] = __float_as_int(e0.y);
    v[1] = e0.z; ix[1] = __float_as_int(e0.w);
    v[2] = e1.x; ix[2] = __float_as_int(e1.y);
    v[3] = e1.z; ix[3] = __float_as_int(e1.w);

#pragma unroll
    for (int d = 1; d < 64; d <<= 1) {
        float bv[4]; int bi[4];
#pragma unroll
        for (int k = 0; k < 4; ++k) {
            bv[k] = __shfl_xor(v[k], d, 64);
            bi[k] = __shfl_xor(ix[k], d, 64);
        }
        merge4(v, ix, bv, bi);
    }
    if (lane == 0) {
        const int b = bw >> 1, which = bw & 1;
        const int base = ((b * Tn + t) * 2 + which) * MT;
#pragma unroll
        for (int k = 0; k < 4; ++k) {
            out_i[base + k] = ix[k];
            out_j[base + k] = k;
        }
    }
}

extern "C" void kernel_launch(void* const* d_in, const int* in_sizes, int n_in,
                              void* d_out, int out_size, void* d_ws, size_t ws_size,
                              hipStream_t stream) {
    const float* pred = (const float*)d_in[0];
    const float* anch = (const float*)d_in[1];
    const float* gt   = (const float*)d_in[2];
    int* out = (int*)d_out;
    float2* partial = (float2*)d_ws;   // 16*64*64*4 float2 = 2 MB
    const int half = Bn * Tn * 2 * MT; // 4096: idx_i block then idx_j block

    dim3 grid1(CHUNKS, 2, Bn);         // 1024 blocks
    matcher_stage1<<<grid1, BLOCK, 0, stream>>>(pred, anch, gt, partial);

    const int tuples = Bn * 2 * Tn;    // 1024 waves
    dim3 grid2(tuples / (BLOCK / 64)); // 256 blocks
    matcher_stage2<<<grid2, BLOCK, 0, stream>>>(partial, out, out + half);
}